// Round 1
// 139.818 us; speedup vs baseline: 1.0601x; 1.0601x over previous
//
#include <hip/hip_runtime.h>
#include <math.h>

#define B_  16
#define C_  256
#define S_  1024
#define NH  4
#define DK  64
#define P3  768   // 3*NH*DK
#define ND  256   // NH*DK

typedef unsigned short u16;
typedef unsigned int   u32;
typedef float  f32x4  __attribute__((ext_vector_type(4)));
typedef short  bf16x8 __attribute__((ext_vector_type(8)));

#define MFMA16(a, b, c) __builtin_amdgcn_mfma_f32_16x16x32_bf16(a, b, c, 0, 0, 0)

// fold softmax scale*log2(e) into q at projection time
#define QSCALE 0.1803368801111137f   // 0.125 * 1.44269504

// counted waitcnt + raw barrier (no vmcnt(0) drain — the __syncthreads killer)
#define WAITVM(N) asm volatile("s_waitcnt vmcnt(" #N ")" ::: "memory")
#define BARRIER() asm volatile("s_barrier" ::: "memory")

__device__ __forceinline__ u16 f2bf(float f) {
    union { float f; u32 u; } x; x.f = f;
    u32 r = x.u + 0x7fffu + ((x.u >> 16) & 1u);   // RNE
    return (u16)(r >> 16);
}

// async global->LDS, 16B per lane; LDS dest is wave-uniform base + lane*16
__device__ __forceinline__ void stage16(const u16* g, u16* l) {
    __builtin_amdgcn_global_load_lds(
        (const __attribute__((address_space(1))) void*)g,
        (__attribute__((address_space(3))) void*)l, 16, 0, 0);
}

// ---------------------------------------------------------------------------
// All transposes in ONE launch (saves a kernel dispatch):
//   z in [0,16): x slice z: [256][1024] -> xt [1024][256] (fp32->bf16)
//   z == 16:     w_proj [256][768] -> wpT [768][256]
//   z == 17:     w_out  [256][256] -> woT [256][256]
// ---------------------------------------------------------------------------
__global__ __launch_bounds__(256) void transpose_all(
    const float* __restrict__ x, u16* __restrict__ xt,
    const float* __restrict__ wp, u16* __restrict__ wpT,
    const float* __restrict__ wo, u16* __restrict__ woT)
{
    const int z = blockIdx.z;
    const float* src;
    u16* dst;
    int Cc;
    if (z < 16)       { src = x + (size_t)z * C_ * S_; dst = xt + (size_t)z * C_ * S_; Cc = S_; }
    else if (z == 16) { src = wp; dst = wpT; Cc = P3; }
    else              { src = wo; dst = woT; Cc = ND; }
    if ((int)blockIdx.x * 64 >= Cc) return;
    const int R = C_;   // 256 rows for all three

    __shared__ float T[64][65];
    const int tid = threadIdx.x;
    const int c0 = blockIdx.x * 64, r0 = blockIdx.y * 64;

    const int l64 = tid & 63, rr0 = tid >> 6;
    #pragma unroll
    for (int t = 0; t < 16; ++t) {
        int rr = rr0 + t * 4;
        T[rr][l64] = src[(size_t)(r0 + rr) * Cc + c0 + l64];
    }
    __syncthreads();
    const int rp = tid & 31;
    const int cb = tid >> 5;
    #pragma unroll
    for (int t = 0; t < 8; ++t) {
        int c = cb + t * 8;
        u32 lo = f2bf(T[2 * rp][c]);
        u32 hi = f2bf(T[2 * rp + 1][c]);
        *(u32*)&dst[(size_t)(c0 + c) * R + r0 + 2 * rp] = lo | (hi << 16);
    }
}

// ---------------------------------------------------------------------------
// QKV projection: 128(M=s) x 64(N=n) tile, 4 waves x (32x64).
// BK=64, 4 phases, DOUBLE-BUFFERED LDS with prefetch (counted vmcnt, raw
// barriers) — loads for phase p+1 stay in flight across phase p's compute.
// q gets QSCALE folded in. v stored TRANSPOSED [bh][dk][s].
// ---------------------------------------------------------------------------
__global__ __launch_bounds__(256) void qkv_mfma(
    const u16* __restrict__ xt, const u16* __restrict__ wpT,
    const float* __restrict__ bp, u16* __restrict__ qo,
    u16* __restrict__ ko, u16* __restrict__ vo)
{
    // 2 x (As 8192 [128 rows x 64 k] + Bs 4096 [64 rows x 64 k]) = 48 KB
    __shared__ __align__(16) u16 SM[24576];

    const int tid = threadIdx.x;
    const int w = tid >> 6, lane = tid & 63;
    const int n_ = lane & 15, quad = lane >> 4;
    const int n0 = blockIdx.x * 64, s0 = blockIdx.y * 128, b = blockIdx.z;

    const u16* ar0 = xt + ((size_t)b * S_ + s0 + (2 * w + 0) * 16 + n_) * C_ + quad * 8;
    const u16* ar1 = xt + ((size_t)b * S_ + s0 + (2 * w + 1) * 16 + n_) * C_ + quad * 8;
    const u16* br  = wpT + (size_t)(n0 + w * 16 + n_) * C_ + quad * 8;

    f32x4 acc[2][4];
    #pragma unroll
    for (int am = 0; am < 2; ++am)
        #pragma unroll
        for (int nf = 0; nf < 4; ++nf)
            #pragma unroll
            for (int r = 0; r < 4; ++r) acc[am][nf][r] = 0.f;

    // prologue: stage phase 0 into buf 0 (6 loads/wave)
    {
        u16* As_ = SM;
        u16* Bs_ = SM + 8192;
        stage16(ar0,      As_ + (4 * w + 0) * 512);
        stage16(ar0 + 32, As_ + (4 * w + 1) * 512);
        stage16(ar1,      As_ + (4 * w + 2) * 512);
        stage16(ar1 + 32, As_ + (4 * w + 3) * 512);
        stage16(br,       Bs_ + (2 * w + 0) * 512);
        stage16(br + 32,  Bs_ + (2 * w + 1) * 512);
    }

    #pragma unroll
    for (int p = 0; p < 4; ++p) {
        u16* As_ = SM + (p & 1) * 12288;
        u16* Bs_ = As_ + 8192;
        if (p < 3) {
            const int pk = (p + 1) * 64;
            u16* An = SM + ((p + 1) & 1) * 12288;
            u16* Bn = An + 8192;
            stage16(ar0 + pk,      An + (4 * w + 0) * 512);
            stage16(ar0 + pk + 32, An + (4 * w + 1) * 512);
            stage16(ar1 + pk,      An + (4 * w + 2) * 512);
            stage16(ar1 + pk + 32, An + (4 * w + 3) * 512);
            stage16(br  + pk,      Bn + (2 * w + 0) * 512);
            stage16(br  + pk + 32, Bn + (2 * w + 1) * 512);
            WAITVM(6);   // phase-p loads done; p+1's 6 stay in flight
        } else {
            WAITVM(0);
        }
        BARRIER();
        #pragma unroll
        for (int kc = 0; kc < 2; ++kc) {
            bf16x8 af0 = *(const bf16x8*)&As_[((2 * w + 0) * 2 + kc) * 512 + lane * 8];
            bf16x8 af1 = *(const bf16x8*)&As_[((2 * w + 1) * 2 + kc) * 512 + lane * 8];
            #pragma unroll
            for (int nf = 0; nf < 4; ++nf) {
                bf16x8 bf = *(const bf16x8*)&Bs_[(nf * 2 + kc) * 512 + lane * 8];
                acc[0][nf] = MFMA16(af0, bf, acc[0][nf]);
                acc[1][nf] = MFMA16(af1, bf, acc[1][nf]);
            }
        }
        if (p < 3) BARRIER();   // all waves done reading buf before restage
    }

    const int hd = n0 / 192, rem = n0 % 192, which = rem / 64;
    const int bh = b * NH + hd;
    float bias[4];
    #pragma unroll
    for (int nf = 0; nf < 4; ++nf) bias[nf] = bp[n0 + nf * 16 + n_];
    const float sc = (which == 0) ? QSCALE : 1.f;

    __syncthreads();   // full drain once; reuse SM for epilogue
    if (which < 2) {
        u16* Cs = SM;                      // [128][72]
        #pragma unroll
        for (int am = 0; am < 2; ++am) {
            int row0 = w * 32 + am * 16 + quad * 4;
            #pragma unroll
            for (int nf = 0; nf < 4; ++nf)
                #pragma unroll
                for (int r = 0; r < 4; ++r)
                    Cs[(row0 + r) * 72 + nf * 16 + n_] =
                        f2bf((acc[am][nf][r] + bias[nf]) * sc);
        }
        __syncthreads();
        u16* dst = (which == 0) ? qo : ko;
        #pragma unroll
        for (int t = 0; t < 4; ++t) {
            int ii = tid + t * 256;
            int row = ii >> 3, c8 = (ii & 7) * 8;
            *(bf16x8*)&dst[((size_t)bh * S_ + s0 + row) * DK + c8] =
                *(const bf16x8*)&Cs[row * 72 + c8];
        }
    } else {
        u16* Cs = SM;                      // [64][136] (dk-major, plain s cols)
        #pragma unroll
        for (int am = 0; am < 2; ++am) {
            int colb = w * 32 + am * 16 + quad * 4;
            #pragma unroll
            for (int nf = 0; nf < 4; ++nf)
                #pragma unroll
                for (int r = 0; r < 4; ++r)
                    Cs[(nf * 16 + n_) * 136 + colb + r] =
                        f2bf(acc[am][nf][r] + bias[nf]);
        }
        __syncthreads();
        #pragma unroll
        for (int t = 0; t < 4; ++t) {
            int ii = tid + t * 256;
            int row = ii >> 4, c8 = (ii & 15) * 8;
            *(bf16x8*)&vo[((size_t)bh * DK + row) * S_ + s0 + c8] =
                *(const bf16x8*)&Cs[row * 136 + c8];
        }
    }
}

// ---------------------------------------------------------------------------
// Flash attention: block = 128 q (4 waves x 32 q), 64-key tiles, no-max
// softmax. S computed TRANSPOSED (A=K with kappa-permuted rows, B=Q).
// NEW: double-buffered K/V staging with counted vmcnt + raw barriers
// (tile t+1's loads in flight across tile t's compute) + setprio on MFMA.
// ---------------------------------------------------------------------------
__global__ __launch_bounds__(256) void attn_mfma(
    const u16* __restrict__ q, const u16* __restrict__ k,
    const u16* __restrict__ vt, u16* __restrict__ obf)
{
    // 2 x (Ks 4096 + Vs 4096) = 32 KB; epilogue reuses first 9216 u16
    __shared__ __align__(16) u16 SM[16384];

    const int tid = threadIdx.x;
    const int w = tid >> 6, lane = tid & 63;
    const int n_ = lane & 15, quad = lane >> 4;
    const int i0 = blockIdx.x * 128;
    const int hd = blockIdx.y, b = blockIdx.z;
    const int bh = b * NH + hd;

    // Q fragments (B-operand; scale pre-folded): query = i0 + w*32 + am*16 + n_
    bf16x8 qf[2][2];
    #pragma unroll
    for (int am = 0; am < 2; ++am) {
        const u16* qrow = q + ((size_t)bh * S_ + i0 + w * 32 + am * 16 + n_) * DK;
        qf[am][0] = *(const bf16x8*)&qrow[quad * 8];
        qf[am][1] = *(const bf16x8*)&qrow[32 + quad * 8];
    }

    // K staging with kappa row permutation (staging wave w = MFMA block nb)
    const int kappa = 32 * (w & 1) + 8 * (n_ >> 2) + 4 * (w >> 1) + (n_ & 3);
    const u16* kbase = k  + ((size_t)bh * S_ + kappa) * DK + quad * 8;
    const u16* vbase = vt + ((size_t)bh * DK + w * 16 + n_) * S_ + quad * 8;

    float lsum[2] = {0.f, 0.f};
    f32x4 oacc[2][4];
    #pragma unroll
    for (int am = 0; am < 2; ++am)
        #pragma unroll
        for (int nd = 0; nd < 4; ++nd)
            #pragma unroll
            for (int r = 0; r < 4; ++r) oacc[am][nd][r] = 0.f;

    // prologue: stage tile 0 into buf 0 (4 loads/wave)
    stage16(kbase,      SM + w * 1024);
    stage16(kbase + 32, SM + w * 1024 + 512);
    stage16(vbase,      SM + 4096 + w * 1024);
    stage16(vbase + 32, SM + 4096 + w * 1024 + 512);

    for (int t = 0; t < 16; ++t) {
        u16* Ks = SM + (t & 1) * 8192;
        u16* Vs = Ks + 4096;
        if (t < 15) {
            const size_t jn = (size_t)(t + 1) * 64;
            u16* Kn = SM + ((t + 1) & 1) * 8192;
            u16* Vn = Kn + 4096;
            stage16(kbase + jn * DK,      Kn + w * 1024);
            stage16(kbase + jn * DK + 32, Kn + w * 1024 + 512);
            stage16(vbase + jn,           Vn + w * 1024);
            stage16(vbase + jn + 32,      Vn + w * 1024 + 512);
            WAITVM(4);   // tile-t loads landed; t+1's 4 stay in flight
        } else {
            WAITVM(0);
        }
        BARRIER();

        // S^T = K Q^T : C rows = permuted keys, cols = queries (n_)
        f32x4 sb[2][4];
        __builtin_amdgcn_s_setprio(1);
        #pragma unroll
        for (int nb = 0; nb < 4; ++nb) {
            bf16x8 kf0 = *(const bf16x8*)&Ks[nb * 1024 + lane * 8];
            bf16x8 kf1 = *(const bf16x8*)&Ks[nb * 1024 + 512 + lane * 8];
            #pragma unroll
            for (int am = 0; am < 2; ++am) {
                f32x4 a; a[0] = a[1] = a[2] = a[3] = 0.f;
                a = MFMA16(kf0, qf[am][0], a);
                a = MFMA16(kf1, qf[am][1], a);
                sb[am][nb] = a;
            }
        }
        __builtin_amdgcn_s_setprio(0);

        // exp2, truncate to bf16, per-lane scalar sum (query=n_ uniform),
        // register repack into PV B-operand layout
        bf16x8 pa[2][2];
        #pragma unroll
        for (int am = 0; am < 2; ++am) {
            u32 tr[4][4];
            #pragma unroll
            for (int nb = 0; nb < 4; ++nb)
                #pragma unroll
                for (int r = 0; r < 4; ++r) {
                    float p = exp2f(sb[am][nb][r]);
                    u32 bits = __float_as_uint(p) & 0xffff0000u;
                    lsum[am] += __uint_as_float(bits);
                    tr[nb][r] = bits;
                }
            union { bf16x8 v; u32 u[4]; } p0, p1;
            p0.u[0] = (tr[0][0] >> 16) | tr[0][1];
            p0.u[1] = (tr[0][2] >> 16) | tr[0][3];
            p0.u[2] = (tr[2][0] >> 16) | tr[2][1];
            p0.u[3] = (tr[2][2] >> 16) | tr[2][3];
            p1.u[0] = (tr[1][0] >> 16) | tr[1][1];
            p1.u[1] = (tr[1][2] >> 16) | tr[1][3];
            p1.u[2] = (tr[3][0] >> 16) | tr[3][1];
            p1.u[3] = (tr[3][2] >> 16) | tr[3][3];
            pa[am][0] = p0.v;
            pa[am][1] = p1.v;
        }

        // O^T += V^T P^T : A = V^T frags (key-slots identity), B = pa
        __builtin_amdgcn_s_setprio(1);
        #pragma unroll
        for (int nd = 0; nd < 4; ++nd) {
            bf16x8 vf0 = *(const bf16x8*)&Vs[nd * 1024 + lane * 8];
            bf16x8 vf1 = *(const bf16x8*)&Vs[nd * 1024 + 512 + lane * 8];
            #pragma unroll
            for (int am = 0; am < 2; ++am) {
                oacc[am][nd] = MFMA16(vf0, pa[am][0], oacc[am][nd]);
                oacc[am][nd] = MFMA16(vf1, pa[am][1], oacc[am][nd]);
            }
        }
        __builtin_amdgcn_s_setprio(0);

        if (t < 15) BARRIER();   // all waves done reading buf before restage
    }

    // total = sum over 4 quads (all 16 in-lane values are for query n_)
    float inv[2];
    #pragma unroll
    for (int am = 0; am < 2; ++am) {
        float s = lsum[am];
        s += __shfl_xor(s, 16);
        s += __shfl_xor(s, 32);
        inv[am] = 1.f / s;
    }

    // epilogue: O^T[dk=nd*16+quad*4+r][query=n_] -> eb[query-local][dk]
    __syncthreads();   // full drain once; reuse SM
    u16* eb = SM + w * 2304;   // [32][72]
    #pragma unroll
    for (int am = 0; am < 2; ++am)
        #pragma unroll
        for (int nd = 0; nd < 4; ++nd) {
            uint2 uv;
            uv.x = (u32)f2bf(oacc[am][nd][0] * inv[am]) |
                   ((u32)f2bf(oacc[am][nd][1] * inv[am]) << 16);
            uv.y = (u32)f2bf(oacc[am][nd][2] * inv[am]) |
                   ((u32)f2bf(oacc[am][nd][3] * inv[am]) << 16);
            *(uint2*)&eb[(am * 16 + n_) * 72 + nd * 16 + quad * 4] = uv;
        }
    __syncthreads();
    #pragma unroll
    for (int t = 0; t < 4; ++t) {
        int ii = lane + t * 64;
        int row = ii >> 3, c8 = (ii & 7) * 8;
        *(bf16x8*)&obf[((size_t)b * S_ + i0 + w * 32 + row) * ND + hd * DK + c8] =
            *(const bf16x8*)&eb[row * 72 + c8];
    }
}

// ---------------------------------------------------------------------------
// Out projection: A = woT (M=c=64), B = obf (N=s=128).
// BK=64, 4 phases, double-buffered prefetch like qkv.
// C[c][s] layout -> direct coalesced stores out[b][c][s] (+bias+residual).
// ---------------------------------------------------------------------------
__global__ __launch_bounds__(256) void out_proj_mfma(
    const u16* __restrict__ obf, const u16* __restrict__ woT,
    const float* __restrict__ bo, const float* __restrict__ x,
    float* __restrict__ out)
{
    // 2 x (Bs 8192 [128 rows x 64 k] + As 4096 [64 rows x 64 k]) = 48 KB
    __shared__ __align__(16) u16 SM[24576];

    const int tid = threadIdx.x;
    const int w = tid >> 6, lane = tid & 63;
    const int n_ = lane & 15, quad = lane >> 4;
    const int c0 = blockIdx.x * 64, s0 = blockIdx.y * 128, b = blockIdx.z;

    const u16* ar  = woT + (size_t)(c0 + w * 16 + n_) * ND + quad * 8;
    const u16* br0 = obf + ((size_t)b * S_ + s0 + (2 * w + 0) * 16 + n_) * ND + quad * 8;
    const u16* br1 = obf + ((size_t)b * S_ + s0 + (2 * w + 1) * 16 + n_) * ND + quad * 8;

    f32x4 acc[2][4];
    #pragma unroll
    for (int nf = 0; nf < 2; ++nf)
        #pragma unroll
        for (int mb = 0; mb < 4; ++mb)
            #pragma unroll
            for (int r = 0; r < 4; ++r) acc[nf][mb][r] = 0.f;

    // prologue: stage phase 0 into buf 0
    {
        u16* Bs_ = SM;
        u16* As_ = SM + 8192;
        stage16(br0,      Bs_ + (4 * w + 0) * 512);
        stage16(br0 + 32, Bs_ + (4 * w + 1) * 512);
        stage16(br1,      Bs_ + (4 * w + 2) * 512);
        stage16(br1 + 32, Bs_ + (4 * w + 3) * 512);
        stage16(ar,       As_ + (2 * w + 0) * 512);
        stage16(ar + 32,  As_ + (2 * w + 1) * 512);
    }

    #pragma unroll
    for (int p = 0; p < 4; ++p) {
        u16* Bs_ = SM + (p & 1) * 12288;
        u16* As_ = Bs_ + 8192;
        if (p < 3) {
            const int pk = (p + 1) * 64;
            u16* Bn = SM + ((p + 1) & 1) * 12288;
            u16* An = Bn + 8192;
            stage16(br0 + pk,      Bn + (4 * w + 0) * 512);
            stage16(br0 + pk + 32, Bn + (4 * w + 1) * 512);
            stage16(br1 + pk,      Bn + (4 * w + 2) * 512);
            stage16(br1 + pk + 32, Bn + (4 * w + 3) * 512);
            stage16(ar  + pk,      An + (2 * w + 0) * 512);
            stage16(ar  + pk + 32, An + (2 * w + 1) * 512);
            WAITVM(6);
        } else {
            WAITVM(0);
        }
        BARRIER();
        #pragma unroll
        for (int kc = 0; kc < 2; ++kc) {
            bf16x8 bf0 = *(const bf16x8*)&Bs_[((2 * w + 0) * 2 + kc) * 512 + lane * 8];
            bf16x8 bf1 = *(const bf16x8*)&Bs_[((2 * w + 1) * 2 + kc) * 512 + lane * 8];
            #pragma unroll
            for (int mb = 0; mb < 4; ++mb) {
                bf16x8 af = *(const bf16x8*)&As_[(mb * 2 + kc) * 512 + lane * 8];
                acc[0][mb] = MFMA16(af, bf0, acc[0][mb]);
                acc[1][mb] = MFMA16(af, bf1, acc[1][mb]);
            }
        }
        if (p < 3) BARRIER();
    }

    // direct epilogue: c = c0+mb*16+quad*4+r, s = s0+w*32+nf*16+n_
    #pragma unroll
    for (int mb = 0; mb < 4; ++mb)
        #pragma unroll
        for (int r = 0; r < 4; ++r) {
            int c = c0 + mb * 16 + quad * 4 + r;
            float bias = bo[c];
            #pragma unroll
            for (int nf = 0; nf < 2; ++nf) {
                size_t idx = ((size_t)b * C_ + c) * S_ + s0 + w * 32 + nf * 16 + n_;
                out[idx] = acc[nf][mb][r] + bias + x[idx];
            }
        }
}

// ---------------------------------------------------------------------------
extern "C" void kernel_launch(void* const* d_in, const int* in_sizes, int n_in,
                              void* d_out, int out_size, void* d_ws, size_t ws_size,
                              hipStream_t stream) {
    const float* x  = (const float*)d_in[0];
    const float* wp = (const float*)d_in[1];
    const float* bp = (const float*)d_in[2];
    const float* wo = (const float*)d_in[3];
    const float* bo = (const float*)d_in[4];
    float* out = (float*)d_out;

    const size_t QKV_E = (size_t)B_ * NH * S_ * DK;   // 4 Mi
    u16* q   = (u16*)d_ws;
    u16* kk  = q   + QKV_E;
    u16* vtp = kk  + QKV_E;
    u16* obf = vtp + QKV_E;                            // B*S*ND
    u16* xt  = obf + (size_t)B_ * S_ * ND;             // B*S*C
    u16* wpT = xt  + (size_t)B_ * S_ * C_;             // P3*C
    u16* woT = wpT + (size_t)P3 * C_;                  // C*ND

    transpose_all<<<dim3(16, 4, 18),             256, 0, stream>>>(x, xt, wp, wpT, wo, woT);
    qkv_mfma     <<<dim3(P3 / 64, S_ / 128, B_), 256, 0, stream>>>(xt, wpT, bp, q, kk, vtp);
    attn_mfma    <<<dim3(S_ / 128, NH, B_),      256, 0, stream>>>(q, kk, vtp, obf);
    out_proj_mfma<<<dim3(C_ / 64, S_ / 128, B_), 256, 0, stream>>>(obf, woT, bo, x, out);
}